// Round 1
// baseline (536.731 us; speedup 1.0000x reference)
//
#include <hip/hip_runtime.h>
#include <math.h>

// ---------------------------------------------------------------------------
// SimSiam head loss, 12 heads, fp32, B=8 H=512 W=768 -> per head (8,3,512,256)
//
// 4 full-data passes (BN stat dependencies force this):
//   pass1: moments of y1 = W1 x + b1            -> bn1 (s1,t1)
//   pass2: moments of y2 = W2 relu(bn1) + b2    -> bn2 (s2,t2)
//   pass3: full 2nd moments of y3 = W3 a2 + b3  -> bn3 (s3,t3) AND bn4 (s4,t4)
//          (y4 = W4 z + b4 is affine in y3, so its mean/var come from the
//           same moment matrix)
//   pass4: pointwise recompute z,p for both branches, cosine loss reduce
//
// Deterministic reductions: per-block double partials in d_ws, tiny reduce
// kernels. No atomics, no memset (all ws slots written before read).
// ---------------------------------------------------------------------------

constexpr int   NH      = 12;
constexpr int   POS     = 131072;                 // positions per (b,head) per channel
constexpr int   NB      = 8;
constexpr long long MLL = (long long)NB * POS;    // 1,048,576 positions per slice
constexpr int   NG      = (int)(MLL / 4);         // 262,144 float4 groups per slice
constexpr int   GX      = 256;                    // blocks per slice (fixed)
constexpr float COS_EPS = 1e-8f;

// ---------------- block reduction: 256 threads -> thread 0 ----------------
template <int K>
__device__ inline void block_reduce_to0(double (&v)[K]) {
#pragma unroll
  for (int off = 32; off > 0; off >>= 1) {
#pragma unroll
    for (int k = 0; k < K; ++k) v[k] += __shfl_down(v[k], off, 64);
  }
  __shared__ double lds[4][K];
  const int lane = threadIdx.x & 63;
  const int wv   = threadIdx.x >> 6;
  if (lane == 0) {
#pragma unroll
    for (int k = 0; k < K; ++k) lds[wv][k] = v[k];
  }
  __syncthreads();
  if (threadIdx.x == 0) {
#pragma unroll
    for (int k = 0; k < K; ++k) v[k] = lds[0][k] + lds[1][k] + lds[2][k] + lds[3][k];
  }
}

// ---------------- pass 1: moments of y1 = W1 x + b1 ----------------
__global__ __launch_bounds__(256) void pass1_kernel(
    const float* __restrict__ x1, const float* __restrict__ x2,
    const float* __restrict__ W1, const float* __restrict__ b1,
    double* __restrict__ P1) {
  const int s = blockIdx.y;
  const int n = s >> 1;
  const float* __restrict__ X = (s & 1) ? x2 : x1;

  float w[3][3], bb[3];
#pragma unroll
  for (int o = 0; o < 3; ++o) {
#pragma unroll
    for (int c = 0; c < 3; ++c) w[o][c] = W1[n * 9 + o * 3 + c];
    bb[o] = b1[n * 3 + o];
  }

  float acc[6] = {0.f, 0.f, 0.f, 0.f, 0.f, 0.f};
  for (int g = blockIdx.x * 256 + threadIdx.x; g < NG; g += GX * 256) {
    const int b   = g >> 15;
    const int pos = (g & 32767) << 2;
    const float* base = X + (size_t)((b * NH + n) * 3) * POS + pos;
    const float4 v0 = *(const float4*)(base);
    const float4 v1 = *(const float4*)(base + POS);
    const float4 v2 = *(const float4*)(base + 2 * POS);
    const float* f0 = (const float*)&v0;
    const float* f1 = (const float*)&v1;
    const float* f2 = (const float*)&v2;
#pragma unroll
    for (int j = 0; j < 4; ++j) {
      const float X0 = f0[j], X1 = f1[j], X2 = f2[j];
#pragma unroll
      for (int o = 0; o < 3; ++o) {
        const float y = fmaf(w[o][0], X0, fmaf(w[o][1], X1, fmaf(w[o][2], X2, bb[o])));
        acc[o]     += y;
        acc[3 + o] += y * y;
      }
    }
  }

  double v[6];
#pragma unroll
  for (int k = 0; k < 6; ++k) v[k] = (double)acc[k];
  block_reduce_to0<6>(v);
  if (threadIdx.x == 0) {
    double* dst = P1 + ((size_t)s * GX + blockIdx.x) * 6;
#pragma unroll
    for (int k = 0; k < 6; ++k) dst[k] = v[k];
  }
}

// ---------------- pass 2: moments of y2 = W2 relu(bn1(y1)) + b2 ----------------
__global__ __launch_bounds__(256) void pass2_kernel(
    const float* __restrict__ x1, const float* __restrict__ x2,
    const float* __restrict__ W1, const float* __restrict__ b1,
    const float* __restrict__ W2, const float* __restrict__ b2,
    const float* __restrict__ derived, double* __restrict__ P2) {
  const int s = blockIdx.y;
  const int n = s >> 1;
  const float* __restrict__ X = (s & 1) ? x2 : x1;

  float w1[3][3], bb1[3], w2[3][3], bb2[3], s1[3], t1[3];
#pragma unroll
  for (int o = 0; o < 3; ++o) {
#pragma unroll
    for (int c = 0; c < 3; ++c) {
      w1[o][c] = W1[n * 9 + o * 3 + c];
      w2[o][c] = W2[n * 9 + o * 3 + c];
    }
    bb1[o] = b1[n * 3 + o];
    bb2[o] = b2[n * 3 + o];
    s1[o]  = derived[s * 20 + o];
    t1[o]  = derived[s * 20 + 3 + o];
  }

  float acc[6] = {0.f, 0.f, 0.f, 0.f, 0.f, 0.f};
  for (int g = blockIdx.x * 256 + threadIdx.x; g < NG; g += GX * 256) {
    const int b   = g >> 15;
    const int pos = (g & 32767) << 2;
    const float* base = X + (size_t)((b * NH + n) * 3) * POS + pos;
    const float4 v0 = *(const float4*)(base);
    const float4 v1 = *(const float4*)(base + POS);
    const float4 v2 = *(const float4*)(base + 2 * POS);
    const float* f0 = (const float*)&v0;
    const float* f1 = (const float*)&v1;
    const float* f2 = (const float*)&v2;
#pragma unroll
    for (int j = 0; j < 4; ++j) {
      const float X0 = f0[j], X1 = f1[j], X2 = f2[j];
      float a[3];
#pragma unroll
      for (int o = 0; o < 3; ++o) {
        const float y = fmaf(w1[o][0], X0, fmaf(w1[o][1], X1, fmaf(w1[o][2], X2, bb1[o])));
        a[o] = fmaxf(0.f, fmaf(s1[o], y, t1[o]));
      }
#pragma unroll
      for (int o = 0; o < 3; ++o) {
        const float y2v = fmaf(w2[o][0], a[0], fmaf(w2[o][1], a[1], fmaf(w2[o][2], a[2], bb2[o])));
        acc[o]     += y2v;
        acc[3 + o] += y2v * y2v;
      }
    }
  }

  double v[6];
#pragma unroll
  for (int k = 0; k < 6; ++k) v[k] = (double)acc[k];
  block_reduce_to0<6>(v);
  if (threadIdx.x == 0) {
    double* dst = P2 + ((size_t)s * GX + blockIdx.x) * 6;
#pragma unroll
    for (int k = 0; k < 6; ++k) dst[k] = v[k];
  }
}

// ---------------- pass 3: full 2nd moments of y3 = W3 a2 + b3 ----------------
__global__ __launch_bounds__(256) void pass3_kernel(
    const float* __restrict__ x1, const float* __restrict__ x2,
    const float* __restrict__ W1, const float* __restrict__ b1,
    const float* __restrict__ W2, const float* __restrict__ b2,
    const float* __restrict__ W3, const float* __restrict__ b3,
    const float* __restrict__ derived, double* __restrict__ P3) {
  const int s = blockIdx.y;
  const int n = s >> 1;
  const float* __restrict__ X = (s & 1) ? x2 : x1;

  float w1[3][3], bb1[3], w2[3][3], bb2[3], w3[3][3], bb3[3];
  float s1[3], t1[3], s2[3], t2[3];
#pragma unroll
  for (int o = 0; o < 3; ++o) {
#pragma unroll
    for (int c = 0; c < 3; ++c) {
      w1[o][c] = W1[n * 9 + o * 3 + c];
      w2[o][c] = W2[n * 9 + o * 3 + c];
      w3[o][c] = W3[n * 9 + o * 3 + c];
    }
    bb1[o] = b1[n * 3 + o];
    bb2[o] = b2[n * 3 + o];
    bb3[o] = b3[n * 3 + o];
    s1[o]  = derived[s * 20 + o];
    t1[o]  = derived[s * 20 + 3 + o];
    s2[o]  = derived[s * 20 + 6 + o];
    t2[o]  = derived[s * 20 + 9 + o];
  }

  float acc[9] = {0.f, 0.f, 0.f, 0.f, 0.f, 0.f, 0.f, 0.f, 0.f};
  for (int g = blockIdx.x * 256 + threadIdx.x; g < NG; g += GX * 256) {
    const int b   = g >> 15;
    const int pos = (g & 32767) << 2;
    const float* base = X + (size_t)((b * NH + n) * 3) * POS + pos;
    const float4 v0 = *(const float4*)(base);
    const float4 v1 = *(const float4*)(base + POS);
    const float4 v2 = *(const float4*)(base + 2 * POS);
    const float* f0 = (const float*)&v0;
    const float* f1 = (const float*)&v1;
    const float* f2 = (const float*)&v2;
#pragma unroll
    for (int j = 0; j < 4; ++j) {
      const float X0 = f0[j], X1 = f1[j], X2 = f2[j];
      float a[3], a2[3], y3[3];
#pragma unroll
      for (int o = 0; o < 3; ++o) {
        const float y = fmaf(w1[o][0], X0, fmaf(w1[o][1], X1, fmaf(w1[o][2], X2, bb1[o])));
        a[o] = fmaxf(0.f, fmaf(s1[o], y, t1[o]));
      }
#pragma unroll
      for (int o = 0; o < 3; ++o) {
        const float y = fmaf(w2[o][0], a[0], fmaf(w2[o][1], a[1], fmaf(w2[o][2], a[2], bb2[o])));
        a2[o] = fmaxf(0.f, fmaf(s2[o], y, t2[o]));
      }
#pragma unroll
      for (int o = 0; o < 3; ++o) {
        y3[o] = fmaf(w3[o][0], a2[0], fmaf(w3[o][1], a2[1], fmaf(w3[o][2], a2[2], bb3[o])));
        acc[o]     += y3[o];
        acc[3 + o] += y3[o] * y3[o];
      }
      acc[6] += y3[0] * y3[1];
      acc[7] += y3[0] * y3[2];
      acc[8] += y3[1] * y3[2];
    }
  }

  double v[9];
#pragma unroll
  for (int k = 0; k < 9; ++k) v[k] = (double)acc[k];
  block_reduce_to0<9>(v);
  if (threadIdx.x == 0) {
    double* dst = P3 + ((size_t)s * GX + blockIdx.x) * 9;
#pragma unroll
    for (int k = 0; k < 9; ++k) dst[k] = v[k];
  }
}

// ---------------- stats reduce for bn1 / bn2 ----------------
__global__ __launch_bounds__(256) void bn_stats_reduce(
    const double* __restrict__ partials,  // [24][GX][6]
    const float* __restrict__ gamma, const float* __restrict__ beta,
    float* __restrict__ derived, int doff) {
  const int s = blockIdx.x;
  const int t = threadIdx.x;
  double v[6];
  const double* p = partials + ((size_t)s * GX + t) * 6;
#pragma unroll
  for (int k = 0; k < 6; ++k) v[k] = p[k];
  block_reduce_to0<6>(v);
  if (t == 0) {
    const int n = s >> 1;
#pragma unroll
    for (int c = 0; c < 3; ++c) {
      const double mean = v[c] / (double)MLL;
      const double var  = v[3 + c] / (double)MLL - mean * mean;
      const double sc   = (double)gamma[n * 3 + c] / sqrt(var + 1e-5);
      derived[s * 20 + doff + c]     = (float)sc;
      derived[s * 20 + doff + 3 + c] = (float)((double)beta[n * 3 + c] - mean * sc);
    }
  }
}

// ---------------- stats reduce for bn3 + bn4 ----------------
__global__ __launch_bounds__(256) void bn_stats3_reduce(
    const double* __restrict__ partials,  // [24][GX][9]
    const float* __restrict__ g3, const float* __restrict__ be3,
    const float* __restrict__ W4, const float* __restrict__ b4,
    const float* __restrict__ g4, const float* __restrict__ be4,
    float* __restrict__ derived) {
  const int s = blockIdx.x;
  const int t = threadIdx.x;
  double v[9];
  const double* p = partials + ((size_t)s * GX + t) * 9;
#pragma unroll
  for (int k = 0; k < 9; ++k) v[k] = p[k];
  block_reduce_to0<9>(v);
  if (t == 0) {
    const int n = s >> 1;
    double mean[3] = {v[0] / (double)MLL, v[1] / (double)MLL, v[2] / (double)MLL};
    double E[3][3];
    E[0][0] = v[3] / (double)MLL;
    E[1][1] = v[4] / (double)MLL;
    E[2][2] = v[5] / (double)MLL;
    E[0][1] = E[1][0] = v[6] / (double)MLL;
    E[0][2] = E[2][0] = v[7] / (double)MLL;
    E[1][2] = E[2][1] = v[8] / (double)MLL;
    double cov[3][3];
    for (int i = 0; i < 3; ++i)
      for (int j = 0; j < 3; ++j) cov[i][j] = E[i][j] - mean[i] * mean[j];

    double s3[3], t3[3];
    for (int c = 0; c < 3; ++c) {
      s3[c] = (double)g3[n * 3 + c] / sqrt(cov[c][c] + 1e-5);
      t3[c] = (double)be3[n * 3 + c] - mean[c] * s3[c];
      derived[s * 20 + 12 + c] = (float)s3[c];
      derived[s * 20 + 15 + c] = (float)t3[c];
    }
    // y4 = W4 . z + b4 = sum_c (W4_c s3_c) y3_c + (b4 + sum_c W4_c t3_c)
    double u[3], dd = (double)b4[n];
    for (int c = 0; c < 3; ++c) {
      u[c] = (double)W4[n * 3 + c] * s3[c];
      dd += (double)W4[n * 3 + c] * t3[c];
    }
    double m4 = dd;
    for (int c = 0; c < 3; ++c) m4 += u[c] * mean[c];
    double v4 = 0.0;
    for (int i = 0; i < 3; ++i)
      for (int j = 0; j < 3; ++j) v4 += u[i] * u[j] * cov[i][j];
    const double s4 = (double)g4[n] / sqrt(v4 + 1e-5);
    derived[s * 20 + 18] = (float)s4;
    derived[s * 20 + 19] = (float)((double)be4[n] - m4 * s4);
  }
}

// ---------------- fused per-position forward chain ----------------
__device__ inline void fwd_chain(
    const float w1[3][3], const float bb1[3],
    const float w2[3][3], const float bb2[3],
    const float w3[3][3], const float bb3[3],
    const float w4[3], float b4s, const float w5[3], const float b5v[3],
    const float* __restrict__ S,  // s1[3] t1[3] s2[3] t2[3] s3[3] t3[3] s4 t4
    float X0, float X1, float X2, float z[3], float p[3]) {
  float a[3], a2[3];
#pragma unroll
  for (int o = 0; o < 3; ++o) {
    const float y = fmaf(w1[o][0], X0, fmaf(w1[o][1], X1, fmaf(w1[o][2], X2, bb1[o])));
    a[o] = fmaxf(0.f, fmaf(S[o], y, S[3 + o]));
  }
#pragma unroll
  for (int o = 0; o < 3; ++o) {
    const float y = fmaf(w2[o][0], a[0], fmaf(w2[o][1], a[1], fmaf(w2[o][2], a[2], bb2[o])));
    a2[o] = fmaxf(0.f, fmaf(S[6 + o], y, S[9 + o]));
  }
  float y4 = b4s;
#pragma unroll
  for (int o = 0; o < 3; ++o) {
    const float y = fmaf(w3[o][0], a2[0], fmaf(w3[o][1], a2[1], fmaf(w3[o][2], a2[2], bb3[o])));
    z[o] = fmaf(S[12 + o], y, S[15 + o]);
    y4 = fmaf(w4[o], z[o], y4);
  }
  const float h = fmaxf(0.f, fmaf(S[18], y4, S[19]));
#pragma unroll
  for (int o = 0; o < 3; ++o) p[o] = fmaf(w5[o], h, b5v[o]);
}

// ---------------- pass 4: cosine loss ----------------
__global__ __launch_bounds__(256) void pass_loss_kernel(
    const float* __restrict__ x1, const float* __restrict__ x2,
    const float* __restrict__ W1, const float* __restrict__ b1,
    const float* __restrict__ W2, const float* __restrict__ b2,
    const float* __restrict__ W3, const float* __restrict__ b3,
    const float* __restrict__ W4, const float* __restrict__ b4,
    const float* __restrict__ W5, const float* __restrict__ b5,
    const float* __restrict__ derived, double* __restrict__ PL) {
  const int n = blockIdx.y;

  float w1[3][3], bb1[3], w2[3][3], bb2[3], w3[3][3], bb3[3];
  float w4[3], b4s, w5[3], b5v[3];
#pragma unroll
  for (int o = 0; o < 3; ++o) {
#pragma unroll
    for (int c = 0; c < 3; ++c) {
      w1[o][c] = W1[n * 9 + o * 3 + c];
      w2[o][c] = W2[n * 9 + o * 3 + c];
      w3[o][c] = W3[n * 9 + o * 3 + c];
    }
    bb1[o] = b1[n * 3 + o];
    bb2[o] = b2[n * 3 + o];
    bb3[o] = b3[n * 3 + o];
    w4[o]  = W4[n * 3 + o];
    w5[o]  = W5[n * 3 + o];
    b5v[o] = b5[n * 3 + o];
  }
  b4s = b4[n];

  float S0[20], S1[20];
#pragma unroll
  for (int k = 0; k < 20; ++k) {
    S0[k] = derived[(n * 2 + 0) * 20 + k];
    S1[k] = derived[(n * 2 + 1) * 20 + k];
  }

  float acc = 0.f;
  for (int g = blockIdx.x * 256 + threadIdx.x; g < NG; g += GX * 256) {
    const int b   = g >> 15;
    const int pos = (g & 32767) << 2;
    const size_t off = (size_t)((b * NH + n) * 3) * POS + pos;
    const float4 u0 = *(const float4*)(x1 + off);
    const float4 u1 = *(const float4*)(x1 + off + POS);
    const float4 u2 = *(const float4*)(x1 + off + 2 * POS);
    const float4 q0 = *(const float4*)(x2 + off);
    const float4 q1 = *(const float4*)(x2 + off + POS);
    const float4 q2 = *(const float4*)(x2 + off + 2 * POS);
    const float* a0 = (const float*)&u0;
    const float* a1 = (const float*)&u1;
    const float* a2p = (const float*)&u2;
    const float* c0 = (const float*)&q0;
    const float* c1 = (const float*)&q1;
    const float* c2 = (const float*)&q2;
#pragma unroll
    for (int j = 0; j < 4; ++j) {
      float z1[3], p1[3], z2[3], p2[3];
      fwd_chain(w1, bb1, w2, bb2, w3, bb3, w4, b4s, w5, b5v, S0,
                a0[j], a1[j], a2p[j], z1, p1);
      fwd_chain(w1, bb1, w2, bb2, w3, bb3, w4, b4s, w5, b5v, S1,
                c0[j], c1[j], c2[j], z2, p2);

      const float d12 = p1[0] * z2[0] + p1[1] * z2[1] + p1[2] * z2[2];
      const float pp1 = p1[0] * p1[0] + p1[1] * p1[1] + p1[2] * p1[2];
      const float zz2 = z2[0] * z2[0] + z2[1] * z2[1] + z2[2] * z2[2];
      const float c12 = d12 / (fmaxf(sqrtf(pp1), COS_EPS) * fmaxf(sqrtf(zz2), COS_EPS));

      const float d21 = p2[0] * z1[0] + p2[1] * z1[1] + p2[2] * z1[2];
      const float pp2 = p2[0] * p2[0] + p2[1] * p2[1] + p2[2] * p2[2];
      const float zz1 = z1[0] * z1[0] + z1[1] * z1[1] + z1[2] * z1[2];
      const float c21 = d21 / (fmaxf(sqrtf(pp2), COS_EPS) * fmaxf(sqrtf(zz1), COS_EPS));

      acc += c12 + c21;
    }
  }

  double v[1] = {(double)acc};
  block_reduce_to0<1>(v);
  if (threadIdx.x == 0) PL[(size_t)n * GX + blockIdx.x] = v[0];
}

// ---------------- finalize ----------------
__global__ __launch_bounds__(256) void finalize_kernel(
    const double* __restrict__ PL, float* __restrict__ out) {
  double v[1] = {0.0};
#pragma unroll
  for (int h = 0; h < NH; ++h) v[0] += PL[(size_t)h * GX + threadIdx.x];
  block_reduce_to0<1>(v);
  if (threadIdx.x == 0) out[0] = (float)(-0.5 * v[0] / (double)MLL);
}

// ---------------- launch ----------------
extern "C" void kernel_launch(void* const* d_in, const int* in_sizes, int n_in,
                              void* d_out, int out_size, void* d_ws, size_t ws_size,
                              hipStream_t stream) {
  const float* x1  = (const float*)d_in[0];
  const float* x2  = (const float*)d_in[1];
  const float* W1  = (const float*)d_in[2];
  const float* b1  = (const float*)d_in[3];
  const float* g1  = (const float*)d_in[4];
  const float* be1 = (const float*)d_in[5];
  const float* W2  = (const float*)d_in[6];
  const float* b2  = (const float*)d_in[7];
  const float* g2  = (const float*)d_in[8];
  const float* be2 = (const float*)d_in[9];
  const float* W3  = (const float*)d_in[10];
  const float* b3  = (const float*)d_in[11];
  const float* g3  = (const float*)d_in[12];
  const float* be3 = (const float*)d_in[13];
  const float* W4  = (const float*)d_in[14];
  const float* b4  = (const float*)d_in[15];
  const float* g4  = (const float*)d_in[16];
  const float* be4 = (const float*)d_in[17];
  const float* W5  = (const float*)d_in[18];
  const float* b5  = (const float*)d_in[19];

  // workspace layout (doubles): P1[24*GX*6] P2[24*GX*6] P3[24*GX*9] PL[12*GX]
  // then floats: derived[24*20]
  double* dws = (double*)d_ws;
  double* P1 = dws;
  double* P2 = dws + 24 * GX * 6;
  double* P3 = dws + 2 * 24 * GX * 6;
  double* PL = dws + 2 * 24 * GX * 6 + 24 * GX * 9;
  float* derived = (float*)(dws + 2 * 24 * GX * 6 + 24 * GX * 9 + NH * GX);

  const dim3 blk(256);
  pass1_kernel<<<dim3(GX, 24), blk, 0, stream>>>(x1, x2, W1, b1, P1);
  bn_stats_reduce<<<24, 256, 0, stream>>>(P1, g1, be1, derived, 0);
  pass2_kernel<<<dim3(GX, 24), blk, 0, stream>>>(x1, x2, W1, b1, W2, b2, derived, P2);
  bn_stats_reduce<<<24, 256, 0, stream>>>(P2, g2, be2, derived, 6);
  pass3_kernel<<<dim3(GX, 24), blk, 0, stream>>>(x1, x2, W1, b1, W2, b2, W3, b3, derived, P3);
  bn_stats3_reduce<<<24, 256, 0, stream>>>(P3, g3, be3, W4, b4, g4, be4, derived);
  pass_loss_kernel<<<dim3(GX, NH), blk, 0, stream>>>(x1, x2, W1, b1, W2, b2, W3, b3,
                                                     W4, b4, W5, b5, derived, PL);
  finalize_kernel<<<1, 256, 0, stream>>>(PL, (float*)d_out);
}

// Round 2
// 515.427 us; speedup vs baseline: 1.0413x; 1.0413x over previous
//
#include <hip/hip_runtime.h>
#include <math.h>

// ---------------------------------------------------------------------------
// SimSiam head loss, 12 heads, fp32, B=8 H=512 W=768 -> per head (8,3,512,256)
//
// 4 full-data passes (BN stat dependencies force this):
//   pass1: moments of y1 = W1 x + b1            -> bn1 (s1,t1)
//   pass2: moments of y2 = W2 relu(bn1) + b2    -> bn2 (s2,t2)
//   pass3: full 2nd moments of y3 = W3 a2 + b3  -> bn3 (s3,t3) AND bn4 (s4,t4)
//   pass4: pointwise recompute z,p for both branches, cosine loss reduce
//
// R1 change: all passes use compile-time-exact trip counts with ALL global
// loads batched up front (12 float4 in flight per thread) to fix the
// latency-bound 2.7 TB/s effective rate seen in R0 (VALUBusy 12%).
// ---------------------------------------------------------------------------

constexpr int   NH      = 12;
constexpr int   POS     = 131072;                 // positions per (b,head) per channel
constexpr int   NB      = 8;
constexpr long long MLL = (long long)NB * POS;    // 1,048,576 positions per slice
constexpr int   NG      = (int)(MLL / 4);         // 262,144 float4 groups per slice
constexpr int   GX      = 256;                    // blocks per slice, passes 1-3
constexpr int   GXL     = 512;                    // blocks per head, pass 4
constexpr float COS_EPS = 1e-8f;

// ---------------- block reduction: 256 threads -> thread 0 ----------------
template <int K>
__device__ inline void block_reduce_to0(double (&v)[K]) {
#pragma unroll
  for (int off = 32; off > 0; off >>= 1) {
#pragma unroll
    for (int k = 0; k < K; ++k) v[k] += __shfl_down(v[k], off, 64);
  }
  __shared__ double lds[4][K];
  const int lane = threadIdx.x & 63;
  const int wv   = threadIdx.x >> 6;
  if (lane == 0) {
#pragma unroll
    for (int k = 0; k < K; ++k) lds[wv][k] = v[k];
  }
  __syncthreads();
  if (threadIdx.x == 0) {
#pragma unroll
    for (int k = 0; k < K; ++k) v[k] = lds[0][k] + lds[1][k] + lds[2][k] + lds[3][k];
  }
}

// batched loader for passes 1-3: 4 iters x 3 channels, all 12 loads up front
__device__ inline void load12(const float* __restrict__ X, int n, int g0,
                              float4 (&r)[4][3]) {
#pragma unroll
  for (int it = 0; it < 4; ++it) {
    const int g   = g0 + it * (GX * 256);
    const int b   = g >> 15;
    const int pos = (g & 32767) << 2;
    const float* base = X + (size_t)((b * NH + n) * 3) * POS + pos;
    r[it][0] = *(const float4*)(base);
    r[it][1] = *(const float4*)(base + POS);
    r[it][2] = *(const float4*)(base + 2 * POS);
  }
}

// ---------------- pass 1: moments of y1 = W1 x + b1 ----------------
__global__ __launch_bounds__(256) void pass1_kernel(
    const float* __restrict__ x1, const float* __restrict__ x2,
    const float* __restrict__ W1, const float* __restrict__ b1,
    double* __restrict__ P1) {
  const int s = blockIdx.y;
  const int n = s >> 1;
  const float* __restrict__ X = (s & 1) ? x2 : x1;

  float w[3][3], bb[3];
#pragma unroll
  for (int o = 0; o < 3; ++o) {
#pragma unroll
    for (int c = 0; c < 3; ++c) w[o][c] = W1[n * 9 + o * 3 + c];
    bb[o] = b1[n * 3 + o];
  }

  float4 r[4][3];
  load12(X, n, blockIdx.x * 256 + threadIdx.x, r);

  float acc[6] = {0.f, 0.f, 0.f, 0.f, 0.f, 0.f};
#pragma unroll
  for (int it = 0; it < 4; ++it) {
    const float* f0 = (const float*)&r[it][0];
    const float* f1 = (const float*)&r[it][1];
    const float* f2 = (const float*)&r[it][2];
#pragma unroll
    for (int j = 0; j < 4; ++j) {
      const float X0 = f0[j], X1 = f1[j], X2 = f2[j];
#pragma unroll
      for (int o = 0; o < 3; ++o) {
        const float y = fmaf(w[o][0], X0, fmaf(w[o][1], X1, fmaf(w[o][2], X2, bb[o])));
        acc[o]     += y;
        acc[3 + o] += y * y;
      }
    }
  }

  double v[6];
#pragma unroll
  for (int k = 0; k < 6; ++k) v[k] = (double)acc[k];
  block_reduce_to0<6>(v);
  if (threadIdx.x == 0) {
    double* dst = P1 + ((size_t)s * GX + blockIdx.x) * 6;
#pragma unroll
    for (int k = 0; k < 6; ++k) dst[k] = v[k];
  }
}

// ---------------- pass 2: moments of y2 = W2 relu(bn1(y1)) + b2 ----------------
__global__ __launch_bounds__(256) void pass2_kernel(
    const float* __restrict__ x1, const float* __restrict__ x2,
    const float* __restrict__ W1, const float* __restrict__ b1,
    const float* __restrict__ W2, const float* __restrict__ b2,
    const float* __restrict__ derived, double* __restrict__ P2) {
  const int s = blockIdx.y;
  const int n = s >> 1;
  const float* __restrict__ X = (s & 1) ? x2 : x1;

  float w1[3][3], bb1[3], w2[3][3], bb2[3], s1[3], t1[3];
#pragma unroll
  for (int o = 0; o < 3; ++o) {
#pragma unroll
    for (int c = 0; c < 3; ++c) {
      w1[o][c] = W1[n * 9 + o * 3 + c];
      w2[o][c] = W2[n * 9 + o * 3 + c];
    }
    bb1[o] = b1[n * 3 + o];
    bb2[o] = b2[n * 3 + o];
    s1[o]  = derived[s * 20 + o];
    t1[o]  = derived[s * 20 + 3 + o];
  }

  float4 r[4][3];
  load12(X, n, blockIdx.x * 256 + threadIdx.x, r);

  float acc[6] = {0.f, 0.f, 0.f, 0.f, 0.f, 0.f};
#pragma unroll
  for (int it = 0; it < 4; ++it) {
    const float* f0 = (const float*)&r[it][0];
    const float* f1 = (const float*)&r[it][1];
    const float* f2 = (const float*)&r[it][2];
#pragma unroll
    for (int j = 0; j < 4; ++j) {
      const float X0 = f0[j], X1 = f1[j], X2 = f2[j];
      float a[3];
#pragma unroll
      for (int o = 0; o < 3; ++o) {
        const float y = fmaf(w1[o][0], X0, fmaf(w1[o][1], X1, fmaf(w1[o][2], X2, bb1[o])));
        a[o] = fmaxf(0.f, fmaf(s1[o], y, t1[o]));
      }
#pragma unroll
      for (int o = 0; o < 3; ++o) {
        const float y2v = fmaf(w2[o][0], a[0], fmaf(w2[o][1], a[1], fmaf(w2[o][2], a[2], bb2[o])));
        acc[o]     += y2v;
        acc[3 + o] += y2v * y2v;
      }
    }
  }

  double v[6];
#pragma unroll
  for (int k = 0; k < 6; ++k) v[k] = (double)acc[k];
  block_reduce_to0<6>(v);
  if (threadIdx.x == 0) {
    double* dst = P2 + ((size_t)s * GX + blockIdx.x) * 6;
#pragma unroll
    for (int k = 0; k < 6; ++k) dst[k] = v[k];
  }
}

// ---------------- pass 3: full 2nd moments of y3 = W3 a2 + b3 ----------------
__global__ __launch_bounds__(256) void pass3_kernel(
    const float* __restrict__ x1, const float* __restrict__ x2,
    const float* __restrict__ W1, const float* __restrict__ b1,
    const float* __restrict__ W2, const float* __restrict__ b2,
    const float* __restrict__ W3, const float* __restrict__ b3,
    const float* __restrict__ derived, double* __restrict__ P3) {
  const int s = blockIdx.y;
  const int n = s >> 1;
  const float* __restrict__ X = (s & 1) ? x2 : x1;

  float w1[3][3], bb1[3], w2[3][3], bb2[3], w3[3][3], bb3[3];
  float s1[3], t1[3], s2[3], t2[3];
#pragma unroll
  for (int o = 0; o < 3; ++o) {
#pragma unroll
    for (int c = 0; c < 3; ++c) {
      w1[o][c] = W1[n * 9 + o * 3 + c];
      w2[o][c] = W2[n * 9 + o * 3 + c];
      w3[o][c] = W3[n * 9 + o * 3 + c];
    }
    bb1[o] = b1[n * 3 + o];
    bb2[o] = b2[n * 3 + o];
    bb3[o] = b3[n * 3 + o];
    s1[o]  = derived[s * 20 + o];
    t1[o]  = derived[s * 20 + 3 + o];
    s2[o]  = derived[s * 20 + 6 + o];
    t2[o]  = derived[s * 20 + 9 + o];
  }

  float4 r[4][3];
  load12(X, n, blockIdx.x * 256 + threadIdx.x, r);

  float acc[9] = {0.f, 0.f, 0.f, 0.f, 0.f, 0.f, 0.f, 0.f, 0.f};
#pragma unroll
  for (int it = 0; it < 4; ++it) {
    const float* f0 = (const float*)&r[it][0];
    const float* f1 = (const float*)&r[it][1];
    const float* f2 = (const float*)&r[it][2];
#pragma unroll
    for (int j = 0; j < 4; ++j) {
      const float X0 = f0[j], X1 = f1[j], X2 = f2[j];
      float a[3], a2[3], y3[3];
#pragma unroll
      for (int o = 0; o < 3; ++o) {
        const float y = fmaf(w1[o][0], X0, fmaf(w1[o][1], X1, fmaf(w1[o][2], X2, bb1[o])));
        a[o] = fmaxf(0.f, fmaf(s1[o], y, t1[o]));
      }
#pragma unroll
      for (int o = 0; o < 3; ++o) {
        const float y = fmaf(w2[o][0], a[0], fmaf(w2[o][1], a[1], fmaf(w2[o][2], a[2], bb2[o])));
        a2[o] = fmaxf(0.f, fmaf(s2[o], y, t2[o]));
      }
#pragma unroll
      for (int o = 0; o < 3; ++o) {
        y3[o] = fmaf(w3[o][0], a2[0], fmaf(w3[o][1], a2[1], fmaf(w3[o][2], a2[2], bb3[o])));
        acc[o]     += y3[o];
        acc[3 + o] += y3[o] * y3[o];
      }
      acc[6] += y3[0] * y3[1];
      acc[7] += y3[0] * y3[2];
      acc[8] += y3[1] * y3[2];
    }
  }

  double v[9];
#pragma unroll
  for (int k = 0; k < 9; ++k) v[k] = (double)acc[k];
  block_reduce_to0<9>(v);
  if (threadIdx.x == 0) {
    double* dst = P3 + ((size_t)s * GX + blockIdx.x) * 9;
#pragma unroll
    for (int k = 0; k < 9; ++k) dst[k] = v[k];
  }
}

// ---------------- stats reduce for bn1 / bn2 ----------------
__global__ __launch_bounds__(256) void bn_stats_reduce(
    const double* __restrict__ partials,  // [24][GX][6]
    const float* __restrict__ gamma, const float* __restrict__ beta,
    float* __restrict__ derived, int doff) {
  const int s = blockIdx.x;
  const int t = threadIdx.x;
  double v[6];
  const double* p = partials + ((size_t)s * GX + t) * 6;
#pragma unroll
  for (int k = 0; k < 6; ++k) v[k] = p[k];
  block_reduce_to0<6>(v);
  if (t == 0) {
    const int n = s >> 1;
#pragma unroll
    for (int c = 0; c < 3; ++c) {
      const double mean = v[c] / (double)MLL;
      const double var  = v[3 + c] / (double)MLL - mean * mean;
      const double sc   = (double)gamma[n * 3 + c] / sqrt(var + 1e-5);
      derived[s * 20 + doff + c]     = (float)sc;
      derived[s * 20 + doff + 3 + c] = (float)((double)beta[n * 3 + c] - mean * sc);
    }
  }
}

// ---------------- stats reduce for bn3 + bn4 ----------------
__global__ __launch_bounds__(256) void bn_stats3_reduce(
    const double* __restrict__ partials,  // [24][GX][9]
    const float* __restrict__ g3, const float* __restrict__ be3,
    const float* __restrict__ W4, const float* __restrict__ b4,
    const float* __restrict__ g4, const float* __restrict__ be4,
    float* __restrict__ derived) {
  const int s = blockIdx.x;
  const int t = threadIdx.x;
  double v[9];
  const double* p = partials + ((size_t)s * GX + t) * 9;
#pragma unroll
  for (int k = 0; k < 9; ++k) v[k] = p[k];
  block_reduce_to0<9>(v);
  if (t == 0) {
    const int n = s >> 1;
    double mean[3] = {v[0] / (double)MLL, v[1] / (double)MLL, v[2] / (double)MLL};
    double E[3][3];
    E[0][0] = v[3] / (double)MLL;
    E[1][1] = v[4] / (double)MLL;
    E[2][2] = v[5] / (double)MLL;
    E[0][1] = E[1][0] = v[6] / (double)MLL;
    E[0][2] = E[2][0] = v[7] / (double)MLL;
    E[1][2] = E[2][1] = v[8] / (double)MLL;
    double cov[3][3];
    for (int i = 0; i < 3; ++i)
      for (int j = 0; j < 3; ++j) cov[i][j] = E[i][j] - mean[i] * mean[j];

    double s3[3], t3[3];
    for (int c = 0; c < 3; ++c) {
      s3[c] = (double)g3[n * 3 + c] / sqrt(cov[c][c] + 1e-5);
      t3[c] = (double)be3[n * 3 + c] - mean[c] * s3[c];
      derived[s * 20 + 12 + c] = (float)s3[c];
      derived[s * 20 + 15 + c] = (float)t3[c];
    }
    // y4 = W4 . z + b4 = sum_c (W4_c s3_c) y3_c + (b4 + sum_c W4_c t3_c)
    double u[3], dd = (double)b4[n];
    for (int c = 0; c < 3; ++c) {
      u[c] = (double)W4[n * 3 + c] * s3[c];
      dd += (double)W4[n * 3 + c] * t3[c];
    }
    double m4 = dd;
    for (int c = 0; c < 3; ++c) m4 += u[c] * mean[c];
    double v4 = 0.0;
    for (int i = 0; i < 3; ++i)
      for (int j = 0; j < 3; ++j) v4 += u[i] * u[j] * cov[i][j];
    const double s4 = (double)g4[n] / sqrt(v4 + 1e-5);
    derived[s * 20 + 18] = (float)s4;
    derived[s * 20 + 19] = (float)((double)be4[n] - m4 * s4);
  }
}

// ---------------- fused per-position forward chain ----------------
__device__ inline void fwd_chain(
    const float w1[3][3], const float bb1[3],
    const float w2[3][3], const float bb2[3],
    const float w3[3][3], const float bb3[3],
    const float w4[3], float b4s, const float w5[3], const float b5v[3],
    const float* __restrict__ S,  // s1[3] t1[3] s2[3] t2[3] s3[3] t3[3] s4 t4
    float X0, float X1, float X2, float z[3], float p[3]) {
  float a[3], a2[3];
#pragma unroll
  for (int o = 0; o < 3; ++o) {
    const float y = fmaf(w1[o][0], X0, fmaf(w1[o][1], X1, fmaf(w1[o][2], X2, bb1[o])));
    a[o] = fmaxf(0.f, fmaf(S[o], y, S[3 + o]));
  }
#pragma unroll
  for (int o = 0; o < 3; ++o) {
    const float y = fmaf(w2[o][0], a[0], fmaf(w2[o][1], a[1], fmaf(w2[o][2], a[2], bb2[o])));
    a2[o] = fmaxf(0.f, fmaf(S[6 + o], y, S[9 + o]));
  }
  float y4 = b4s;
#pragma unroll
  for (int o = 0; o < 3; ++o) {
    const float y = fmaf(w3[o][0], a2[0], fmaf(w3[o][1], a2[1], fmaf(w3[o][2], a2[2], bb3[o])));
    z[o] = fmaf(S[12 + o], y, S[15 + o]);
    y4 = fmaf(w4[o], z[o], y4);
  }
  const float h = fmaxf(0.f, fmaf(S[18], y4, S[19]));
#pragma unroll
  for (int o = 0; o < 3; ++o) p[o] = fmaf(w5[o], h, b5v[o]);
}

// ---------------- pass 4: cosine loss (GXL=512 blocks/head, 2 iters) --------
__global__ __launch_bounds__(256) void pass_loss_kernel(
    const float* __restrict__ x1, const float* __restrict__ x2,
    const float* __restrict__ W1, const float* __restrict__ b1,
    const float* __restrict__ W2, const float* __restrict__ b2,
    const float* __restrict__ W3, const float* __restrict__ b3,
    const float* __restrict__ W4, const float* __restrict__ b4,
    const float* __restrict__ W5, const float* __restrict__ b5,
    const float* __restrict__ derived, double* __restrict__ PL) {
  const int n = blockIdx.y;

  float w1[3][3], bb1[3], w2[3][3], bb2[3], w3[3][3], bb3[3];
  float w4[3], b4s, w5[3], b5v[3];
#pragma unroll
  for (int o = 0; o < 3; ++o) {
#pragma unroll
    for (int c = 0; c < 3; ++c) {
      w1[o][c] = W1[n * 9 + o * 3 + c];
      w2[o][c] = W2[n * 9 + o * 3 + c];
      w3[o][c] = W3[n * 9 + o * 3 + c];
    }
    bb1[o] = b1[n * 3 + o];
    bb2[o] = b2[n * 3 + o];
    bb3[o] = b3[n * 3 + o];
    w4[o]  = W4[n * 3 + o];
    w5[o]  = W5[n * 3 + o];
    b5v[o] = b5[n * 3 + o];
  }
  b4s = b4[n];

  float S0[20], S1[20];
#pragma unroll
  for (int k = 0; k < 20; ++k) {
    S0[k] = derived[(n * 2 + 0) * 20 + k];
    S1[k] = derived[(n * 2 + 1) * 20 + k];
  }

  // batch all 12 loads (2 iters x (3 ch x 2 branches)) up front
  const int g0 = blockIdx.x * 256 + threadIdx.x;   // 0 .. 131071
  float4 r1[2][3], r2[2][3];
#pragma unroll
  for (int it = 0; it < 2; ++it) {
    const int g   = g0 + it * (GXL * 256);
    const int b   = g >> 15;
    const int pos = (g & 32767) << 2;
    const size_t off = (size_t)((b * NH + n) * 3) * POS + pos;
    r1[it][0] = *(const float4*)(x1 + off);
    r1[it][1] = *(const float4*)(x1 + off + POS);
    r1[it][2] = *(const float4*)(x1 + off + 2 * POS);
    r2[it][0] = *(const float4*)(x2 + off);
    r2[it][1] = *(const float4*)(x2 + off + POS);
    r2[it][2] = *(const float4*)(x2 + off + 2 * POS);
  }

  float acc = 0.f;
#pragma unroll
  for (int it = 0; it < 2; ++it) {
    const float* a0  = (const float*)&r1[it][0];
    const float* a1  = (const float*)&r1[it][1];
    const float* a2p = (const float*)&r1[it][2];
    const float* c0  = (const float*)&r2[it][0];
    const float* c1  = (const float*)&r2[it][1];
    const float* c2  = (const float*)&r2[it][2];
#pragma unroll
    for (int j = 0; j < 4; ++j) {
      float z1[3], p1[3], z2[3], p2[3];
      fwd_chain(w1, bb1, w2, bb2, w3, bb3, w4, b4s, w5, b5v, S0,
                a0[j], a1[j], a2p[j], z1, p1);
      fwd_chain(w1, bb1, w2, bb2, w3, bb3, w4, b4s, w5, b5v, S1,
                c0[j], c1[j], c2[j], z2, p2);

      const float d12 = p1[0] * z2[0] + p1[1] * z2[1] + p1[2] * z2[2];
      const float pp1 = p1[0] * p1[0] + p1[1] * p1[1] + p1[2] * p1[2];
      const float zz2 = z2[0] * z2[0] + z2[1] * z2[1] + z2[2] * z2[2];
      const float c12 = d12 / (fmaxf(sqrtf(pp1), COS_EPS) * fmaxf(sqrtf(zz2), COS_EPS));

      const float d21 = p2[0] * z1[0] + p2[1] * z1[1] + p2[2] * z1[2];
      const float pp2 = p2[0] * p2[0] + p2[1] * p2[1] + p2[2] * p2[2];
      const float zz1 = z1[0] * z1[0] + z1[1] * z1[1] + z1[2] * z1[2];
      const float c21 = d21 / (fmaxf(sqrtf(pp2), COS_EPS) * fmaxf(sqrtf(zz1), COS_EPS));

      acc += c12 + c21;
    }
  }

  double v[1] = {(double)acc};
  block_reduce_to0<1>(v);
  if (threadIdx.x == 0) PL[(size_t)n * GXL + blockIdx.x] = v[0];
}

// ---------------- finalize ----------------
__global__ __launch_bounds__(256) void finalize_kernel(
    const double* __restrict__ PL, float* __restrict__ out) {
  double v[1] = {0.0};
#pragma unroll
  for (int h = 0; h < NH; ++h) {
    v[0] += PL[(size_t)h * GXL + threadIdx.x];
    v[0] += PL[(size_t)h * GXL + 256 + threadIdx.x];
  }
  block_reduce_to0<1>(v);
  if (threadIdx.x == 0) out[0] = (float)(-0.5 * v[0] / (double)MLL);
}

// ---------------- launch ----------------
extern "C" void kernel_launch(void* const* d_in, const int* in_sizes, int n_in,
                              void* d_out, int out_size, void* d_ws, size_t ws_size,
                              hipStream_t stream) {
  const float* x1  = (const float*)d_in[0];
  const float* x2  = (const float*)d_in[1];
  const float* W1  = (const float*)d_in[2];
  const float* b1  = (const float*)d_in[3];
  const float* g1  = (const float*)d_in[4];
  const float* be1 = (const float*)d_in[5];
  const float* W2  = (const float*)d_in[6];
  const float* b2  = (const float*)d_in[7];
  const float* g2  = (const float*)d_in[8];
  const float* be2 = (const float*)d_in[9];
  const float* W3  = (const float*)d_in[10];
  const float* b3  = (const float*)d_in[11];
  const float* g3  = (const float*)d_in[12];
  const float* be3 = (const float*)d_in[13];
  const float* W4  = (const float*)d_in[14];
  const float* b4  = (const float*)d_in[15];
  const float* g4  = (const float*)d_in[16];
  const float* be4 = (const float*)d_in[17];
  const float* W5  = (const float*)d_in[18];
  const float* b5  = (const float*)d_in[19];

  // workspace layout (doubles): P1[24*GX*6] P2[24*GX*6] P3[24*GX*9] PL[12*GXL]
  // then floats: derived[24*20]
  double* dws = (double*)d_ws;
  double* P1 = dws;
  double* P2 = dws + 24 * GX * 6;
  double* P3 = dws + 2 * 24 * GX * 6;
  double* PL = dws + 2 * 24 * GX * 6 + 24 * GX * 9;
  float* derived = (float*)(dws + 2 * 24 * GX * 6 + 24 * GX * 9 + NH * GXL);

  const dim3 blk(256);
  pass1_kernel<<<dim3(GX, 24), blk, 0, stream>>>(x1, x2, W1, b1, P1);
  bn_stats_reduce<<<24, 256, 0, stream>>>(P1, g1, be1, derived, 0);
  pass2_kernel<<<dim3(GX, 24), blk, 0, stream>>>(x1, x2, W1, b1, W2, b2, derived, P2);
  bn_stats_reduce<<<24, 256, 0, stream>>>(P2, g2, be2, derived, 6);
  pass3_kernel<<<dim3(GX, 24), blk, 0, stream>>>(x1, x2, W1, b1, W2, b2, W3, b3, derived, P3);
  bn_stats3_reduce<<<24, 256, 0, stream>>>(P3, g3, be3, W4, b4, g4, be4, derived);
  pass_loss_kernel<<<dim3(GXL, NH), blk, 0, stream>>>(x1, x2, W1, b1, W2, b2, W3, b3,
                                                      W4, b4, W5, b5, derived, PL);
  finalize_kernel<<<1, 256, 0, stream>>>(PL, (float*)d_out);
}

// Round 3
// 511.401 us; speedup vs baseline: 1.0495x; 1.0079x over previous
//
#include <hip/hip_runtime.h>
#include <math.h>

// ---------------------------------------------------------------------------
// SimSiam head loss, 12 heads, fp32 in, B=8 H=512 W=768 -> per head (8,3,512,256)
//
// R2 structure (traffic reduction):
//   passA: 9 raw moments of x per slice (bn1 analytic: y1 is linear in x)
//          + writes bf16 copy of x1,x2 into d_ws (if ws_size permits)
//   passB: moments of y2 = W2 relu(bn1) + b2  [reads bf16]  -> bn2
//   passC: full 2nd moments of y3             [reads bf16]  -> bn3 + bn4
//   passD: recompute z,p both branches, cosine loss reduce [reads bf16]
// bf16 working set = 151 MB < 256 MB L3 -> passes B-D mostly L3-served.
// Fallback (<152 MB ws): same kernels, fp32 reads (template<bool BF16>).
// ---------------------------------------------------------------------------

typedef unsigned short ushort_t;
typedef unsigned int uint_t;

constexpr int   NH      = 12;
constexpr int   POS     = 131072;               // floats per channel per (b,head)
constexpr int   NB      = 8;
constexpr long long MLL = (long long)NB * POS;  // 1,048,576 positions per slice
constexpr int   CSPAN   = POS / 16;             // 8192 floats/channel per block
constexpr int   SBLK    = 128;                  // blocks per slice = 8 b * 16 x
constexpr int   NTOT    = NB * NH * 3 * POS;    // 37,748,736 elements per latent
constexpr float COS_EPS = 1e-8f;

// ws bytes needed for the bf16 path
constexpr size_t XB_BYTES   = (size_t)NTOT * 2;                        // per latent
constexpr size_t DBL_COUNT  = (size_t)24 * SBLK * 9 + (size_t)24 * SBLK * 6 +
                              (size_t)24 * SBLK * 9 + (size_t)12 * SBLK;
constexpr size_t NEED_BYTES = 2 * XB_BYTES + DBL_COUNT * 8 + 480 * 4;

// ---------------- block reduction: 256 threads -> thread 0 ----------------
template <int K>
__device__ inline void block_reduce_to0(double (&v)[K]) {
#pragma unroll
  for (int off = 32; off > 0; off >>= 1) {
#pragma unroll
    for (int k = 0; k < K; ++k) v[k] += __shfl_down(v[k], off, 64);
  }
  __shared__ double lds[4][K];
  const int lane = threadIdx.x & 63;
  const int wv   = threadIdx.x >> 6;
  if (lane == 0) {
#pragma unroll
    for (int k = 0; k < K; ++k) lds[wv][k] = v[k];
  }
  __syncthreads();
  if (threadIdx.x == 0) {
#pragma unroll
    for (int k = 0; k < K; ++k) v[k] = lds[0][k] + lds[1][k] + lds[2][k] + lds[3][k];
  }
}

// ---------------- bf16 helpers ----------------
__device__ inline uint_t pack2bf(float lo, float hi) {   // RNE pack
  uint_t ul = __float_as_uint(lo);
  uint_t uh = __float_as_uint(hi);
  ul = ul + 0x7FFFu + ((ul >> 16) & 1u);
  uh = uh + 0x7FFFu + ((uh >> 16) & 1u);
  return (ul >> 16) | (uh & 0xFFFF0000u);
}

__device__ inline void unpack8(const uint4 v, float (&f)[8]) {
  const uint_t w0 = v.x, w1 = v.y, w2 = v.z, w3 = v.w;
  f[0] = __uint_as_float(w0 << 16); f[1] = __uint_as_float(w0 & 0xFFFF0000u);
  f[2] = __uint_as_float(w1 << 16); f[3] = __uint_as_float(w1 & 0xFFFF0000u);
  f[4] = __uint_as_float(w2 << 16); f[5] = __uint_as_float(w2 & 0xFFFF0000u);
  f[6] = __uint_as_float(w3 << 16); f[7] = __uint_as_float(w3 & 0xFFFF0000u);
}

// load 8 consecutive positions for all 3 channels
template <bool BF16>
__device__ inline void load_ch3(const float* __restrict__ X,
                                const ushort_t* __restrict__ XB,
                                size_t eoff, float (&f)[3][8]) {
#pragma unroll
  for (int c = 0; c < 3; ++c) {
    const size_t a = eoff + (size_t)c * POS;
    if constexpr (BF16) {
      const uint4 v = *(const uint4*)(XB + a);
      unpack8(v, f[c]);
    } else {
      const float4 u0 = *(const float4*)(X + a);
      const float4 u1 = *(const float4*)(X + a + 4);
      f[c][0] = u0.x; f[c][1] = u0.y; f[c][2] = u0.z; f[c][3] = u0.w;
      f[c][4] = u1.x; f[c][5] = u1.y; f[c][6] = u1.z; f[c][7] = u1.w;
    }
  }
}

// ---------------- pass A: raw moments of x (+ bf16 store) ----------------
template <bool STORE>
__global__ __launch_bounds__(256) void passA_kernel(
    const float* __restrict__ x1, const float* __restrict__ x2,
    ushort_t* __restrict__ xb1, ushort_t* __restrict__ xb2,
    double* __restrict__ P0) {
  const int u = blockIdx.y;        // 0..191
  const int s = u % 24;
  const int b = u / 24;
  const int n = s >> 1;
  const float* __restrict__ X = (s & 1) ? x2 : x1;
  ushort_t* __restrict__ XB = (s & 1) ? xb2 : xb1;
  const size_t off0 = (size_t)((b * NH + n) * 3) * POS + (size_t)blockIdx.x * CSPAN;

  float acc[9] = {0.f, 0.f, 0.f, 0.f, 0.f, 0.f, 0.f, 0.f, 0.f};
#pragma unroll
  for (int i = 0; i < 8; ++i) {
    const int idx = i * 1024 + threadIdx.x * 4;
    float4 v[3];
#pragma unroll
    for (int c = 0; c < 3; ++c)
      v[c] = *(const float4*)(X + off0 + (size_t)c * POS + idx);
    if constexpr (STORE) {
#pragma unroll
      for (int c = 0; c < 3; ++c) {
        uint2 h;
        h.x = pack2bf(v[c].x, v[c].y);
        h.y = pack2bf(v[c].z, v[c].w);
        *(uint2*)(XB + off0 + (size_t)c * POS + idx) = h;
      }
    }
    const float* f0 = (const float*)&v[0];
    const float* f1 = (const float*)&v[1];
    const float* f2 = (const float*)&v[2];
#pragma unroll
    for (int j = 0; j < 4; ++j) {
      const float X0 = f0[j], X1 = f1[j], X2 = f2[j];
      acc[0] += X0;      acc[1] += X1;      acc[2] += X2;
      acc[3] += X0 * X0; acc[4] += X1 * X1; acc[5] += X2 * X2;
      acc[6] += X0 * X1; acc[7] += X0 * X2; acc[8] += X1 * X2;
    }
  }

  double v9[9];
#pragma unroll
  for (int k = 0; k < 9; ++k) v9[k] = (double)acc[k];
  block_reduce_to0<9>(v9);
  if (threadIdx.x == 0) {
    double* dst = P0 + ((size_t)s * SBLK + b * 16 + blockIdx.x) * 9;
#pragma unroll
    for (int k = 0; k < 9; ++k) dst[k] = v9[k];
  }
}

// ---------------- bn1 analytic from x moments ----------------
__global__ __launch_bounds__(256) void bn_statsA_kernel(
    const double* __restrict__ P0, const float* __restrict__ W1,
    const float* __restrict__ b1, const float* __restrict__ g1,
    const float* __restrict__ be1, float* __restrict__ derived) {
  const int s = blockIdx.x;
  const int t = threadIdx.x;
  const int n = s >> 1;
  double v[9] = {0, 0, 0, 0, 0, 0, 0, 0, 0};
  if (t < SBLK) {
    const double* p = P0 + ((size_t)s * SBLK + t) * 9;
#pragma unroll
    for (int k = 0; k < 9; ++k) v[k] = p[k];
  }
  block_reduce_to0<9>(v);
  if (t == 0) {
    const double M = (double)MLL;
    double m[3] = {v[0] / M, v[1] / M, v[2] / M};
    double C00 = v[3] / M - m[0] * m[0];
    double C11 = v[4] / M - m[1] * m[1];
    double C22 = v[5] / M - m[2] * m[2];
    double C01 = v[6] / M - m[0] * m[1];
    double C02 = v[7] / M - m[0] * m[2];
    double C12 = v[8] / M - m[1] * m[2];
    for (int o = 0; o < 3; ++o) {
      const double w0 = W1[n * 9 + o * 3 + 0];
      const double w1v = W1[n * 9 + o * 3 + 1];
      const double w2v = W1[n * 9 + o * 3 + 2];
      const double my = w0 * m[0] + w1v * m[1] + w2v * m[2] + (double)b1[n * 3 + o];
      const double vy = w0 * w0 * C00 + w1v * w1v * C11 + w2v * w2v * C22 +
                        2.0 * (w0 * w1v * C01 + w0 * w2v * C02 + w1v * w2v * C12);
      const double sc = (double)g1[n * 3 + o] / sqrt(vy + 1e-5);
      derived[s * 20 + o]     = (float)sc;
      derived[s * 20 + 3 + o] = (float)((double)be1[n * 3 + o] - my * sc);
    }
  }
}

// ---------------- pass B: moments of y2 ----------------
template <bool BF16>
__global__ __launch_bounds__(256) void passB_kernel(
    const float* __restrict__ x1, const float* __restrict__ x2,
    const ushort_t* __restrict__ xb1, const ushort_t* __restrict__ xb2,
    const float* __restrict__ W1, const float* __restrict__ b1,
    const float* __restrict__ W2, const float* __restrict__ b2,
    const float* __restrict__ derived, double* __restrict__ P2) {
  const int u = blockIdx.y;
  const int s = u % 24;
  const int b = u / 24;
  const int n = s >> 1;
  const float* __restrict__ X = (s & 1) ? x2 : x1;
  const ushort_t* __restrict__ XB = (s & 1) ? xb2 : xb1;
  const size_t off0 = (size_t)((b * NH + n) * 3) * POS + (size_t)blockIdx.x * CSPAN;

  float w1[3][3], bb1[3], w2[3][3], bb2[3], s1[3], t1[3];
#pragma unroll
  for (int o = 0; o < 3; ++o) {
#pragma unroll
    for (int c = 0; c < 3; ++c) {
      w1[o][c] = W1[n * 9 + o * 3 + c];
      w2[o][c] = W2[n * 9 + o * 3 + c];
    }
    bb1[o] = b1[n * 3 + o];
    bb2[o] = b2[n * 3 + o];
    s1[o]  = derived[s * 20 + o];
    t1[o]  = derived[s * 20 + 3 + o];
  }

  float acc[6] = {0.f, 0.f, 0.f, 0.f, 0.f, 0.f};
#pragma unroll 2
  for (int i = 0; i < 4; ++i) {
    const size_t eoff = off0 + i * 2048 + threadIdx.x * 8;
    float f[3][8];
    load_ch3<BF16>(X, XB, eoff, f);
#pragma unroll
    for (int j = 0; j < 8; ++j) {
      const float X0 = f[0][j], X1 = f[1][j], X2 = f[2][j];
      float a[3];
#pragma unroll
      for (int o = 0; o < 3; ++o) {
        const float y = fmaf(w1[o][0], X0, fmaf(w1[o][1], X1, fmaf(w1[o][2], X2, bb1[o])));
        a[o] = fmaxf(0.f, fmaf(s1[o], y, t1[o]));
      }
#pragma unroll
      for (int o = 0; o < 3; ++o) {
        const float y2v = fmaf(w2[o][0], a[0], fmaf(w2[o][1], a[1], fmaf(w2[o][2], a[2], bb2[o])));
        acc[o]     += y2v;
        acc[3 + o] += y2v * y2v;
      }
    }
  }

  double v[6];
#pragma unroll
  for (int k = 0; k < 6; ++k) v[k] = (double)acc[k];
  block_reduce_to0<6>(v);
  if (threadIdx.x == 0) {
    double* dst = P2 + ((size_t)s * SBLK + b * 16 + blockIdx.x) * 6;
#pragma unroll
    for (int k = 0; k < 6; ++k) dst[k] = v[k];
  }
}

// ---------------- bn2 stats ----------------
__global__ __launch_bounds__(256) void bn_statsB_kernel(
    const double* __restrict__ P2, const float* __restrict__ gamma,
    const float* __restrict__ beta, float* __restrict__ derived) {
  const int s = blockIdx.x;
  const int t = threadIdx.x;
  const int n = s >> 1;
  double v[6] = {0, 0, 0, 0, 0, 0};
  if (t < SBLK) {
    const double* p = P2 + ((size_t)s * SBLK + t) * 6;
#pragma unroll
    for (int k = 0; k < 6; ++k) v[k] = p[k];
  }
  block_reduce_to0<6>(v);
  if (t == 0) {
#pragma unroll
    for (int c = 0; c < 3; ++c) {
      const double mean = v[c] / (double)MLL;
      const double var  = v[3 + c] / (double)MLL - mean * mean;
      const double sc   = (double)gamma[n * 3 + c] / sqrt(var + 1e-5);
      derived[s * 20 + 6 + c] = (float)sc;
      derived[s * 20 + 9 + c] = (float)((double)beta[n * 3 + c] - mean * sc);
    }
  }
}

// ---------------- pass C: full 2nd moments of y3 ----------------
template <bool BF16>
__global__ __launch_bounds__(256) void passC_kernel(
    const float* __restrict__ x1, const float* __restrict__ x2,
    const ushort_t* __restrict__ xb1, const ushort_t* __restrict__ xb2,
    const float* __restrict__ W1, const float* __restrict__ b1,
    const float* __restrict__ W2, const float* __restrict__ b2,
    const float* __restrict__ W3, const float* __restrict__ b3,
    const float* __restrict__ derived, double* __restrict__ P3) {
  const int u = blockIdx.y;
  const int s = u % 24;
  const int b = u / 24;
  const int n = s >> 1;
  const float* __restrict__ X = (s & 1) ? x2 : x1;
  const ushort_t* __restrict__ XB = (s & 1) ? xb2 : xb1;
  const size_t off0 = (size_t)((b * NH + n) * 3) * POS + (size_t)blockIdx.x * CSPAN;

  float w1[3][3], bb1[3], w2[3][3], bb2[3], w3[3][3], bb3[3];
  float s1[3], t1[3], s2[3], t2[3];
#pragma unroll
  for (int o = 0; o < 3; ++o) {
#pragma unroll
    for (int c = 0; c < 3; ++c) {
      w1[o][c] = W1[n * 9 + o * 3 + c];
      w2[o][c] = W2[n * 9 + o * 3 + c];
      w3[o][c] = W3[n * 9 + o * 3 + c];
    }
    bb1[o] = b1[n * 3 + o];
    bb2[o] = b2[n * 3 + o];
    bb3[o] = b3[n * 3 + o];
    s1[o]  = derived[s * 20 + o];
    t1[o]  = derived[s * 20 + 3 + o];
    s2[o]  = derived[s * 20 + 6 + o];
    t2[o]  = derived[s * 20 + 9 + o];
  }

  float acc[9] = {0.f, 0.f, 0.f, 0.f, 0.f, 0.f, 0.f, 0.f, 0.f};
#pragma unroll 2
  for (int i = 0; i < 4; ++i) {
    const size_t eoff = off0 + i * 2048 + threadIdx.x * 8;
    float f[3][8];
    load_ch3<BF16>(X, XB, eoff, f);
#pragma unroll
    for (int j = 0; j < 8; ++j) {
      const float X0 = f[0][j], X1 = f[1][j], X2 = f[2][j];
      float a[3], a2[3], y3[3];
#pragma unroll
      for (int o = 0; o < 3; ++o) {
        const float y = fmaf(w1[o][0], X0, fmaf(w1[o][1], X1, fmaf(w1[o][2], X2, bb1[o])));
        a[o] = fmaxf(0.f, fmaf(s1[o], y, t1[o]));
      }
#pragma unroll
      for (int o = 0; o < 3; ++o) {
        const float y = fmaf(w2[o][0], a[0], fmaf(w2[o][1], a[1], fmaf(w2[o][2], a[2], bb2[o])));
        a2[o] = fmaxf(0.f, fmaf(s2[o], y, t2[o]));
      }
#pragma unroll
      for (int o = 0; o < 3; ++o) {
        y3[o] = fmaf(w3[o][0], a2[0], fmaf(w3[o][1], a2[1], fmaf(w3[o][2], a2[2], bb3[o])));
        acc[o]     += y3[o];
        acc[3 + o] += y3[o] * y3[o];
      }
      acc[6] += y3[0] * y3[1];
      acc[7] += y3[0] * y3[2];
      acc[8] += y3[1] * y3[2];
    }
  }

  double v[9];
#pragma unroll
  for (int k = 0; k < 9; ++k) v[k] = (double)acc[k];
  block_reduce_to0<9>(v);
  if (threadIdx.x == 0) {
    double* dst = P3 + ((size_t)s * SBLK + b * 16 + blockIdx.x) * 9;
#pragma unroll
    for (int k = 0; k < 9; ++k) dst[k] = v[k];
  }
}

// ---------------- bn3 + bn4 stats ----------------
__global__ __launch_bounds__(256) void bn_statsC_kernel(
    const double* __restrict__ P3, const float* __restrict__ g3,
    const float* __restrict__ be3, const float* __restrict__ W4,
    const float* __restrict__ b4, const float* __restrict__ g4,
    const float* __restrict__ be4, float* __restrict__ derived) {
  const int s = blockIdx.x;
  const int t = threadIdx.x;
  const int n = s >> 1;
  double v[9] = {0, 0, 0, 0, 0, 0, 0, 0, 0};
  if (t < SBLK) {
    const double* p = P3 + ((size_t)s * SBLK + t) * 9;
#pragma unroll
    for (int k = 0; k < 9; ++k) v[k] = p[k];
  }
  block_reduce_to0<9>(v);
  if (t == 0) {
    const double M = (double)MLL;
    double mean[3] = {v[0] / M, v[1] / M, v[2] / M};
    double cov[3][3];
    cov[0][0] = v[3] / M - mean[0] * mean[0];
    cov[1][1] = v[4] / M - mean[1] * mean[1];
    cov[2][2] = v[5] / M - mean[2] * mean[2];
    cov[0][1] = cov[1][0] = v[6] / M - mean[0] * mean[1];
    cov[0][2] = cov[2][0] = v[7] / M - mean[0] * mean[2];
    cov[1][2] = cov[2][1] = v[8] / M - mean[1] * mean[2];

    double s3[3], t3[3];
    for (int c = 0; c < 3; ++c) {
      s3[c] = (double)g3[n * 3 + c] / sqrt(cov[c][c] + 1e-5);
      t3[c] = (double)be3[n * 3 + c] - mean[c] * s3[c];
      derived[s * 20 + 12 + c] = (float)s3[c];
      derived[s * 20 + 15 + c] = (float)t3[c];
    }
    double u[3], dd = (double)b4[n];
    for (int c = 0; c < 3; ++c) {
      u[c] = (double)W4[n * 3 + c] * s3[c];
      dd += (double)W4[n * 3 + c] * t3[c];
    }
    double m4 = dd;
    for (int c = 0; c < 3; ++c) m4 += u[c] * mean[c];
    double v4 = 0.0;
    for (int i = 0; i < 3; ++i)
      for (int j = 0; j < 3; ++j) v4 += u[i] * u[j] * cov[i][j];
    const double s4 = (double)g4[n] / sqrt(v4 + 1e-5);
    derived[s * 20 + 18] = (float)s4;
    derived[s * 20 + 19] = (float)((double)be4[n] - m4 * s4);
  }
}

// ---------------- fused per-position forward chain ----------------
__device__ inline void fwd_chain(
    const float w1[3][3], const float bb1[3],
    const float w2[3][3], const float bb2[3],
    const float w3[3][3], const float bb3[3],
    const float w4[3], float b4s, const float w5[3], const float b5v[3],
    const float* S, float X0, float X1, float X2, float z[3], float p[3]) {
  float a[3], a2[3];
#pragma unroll
  for (int o = 0; o < 3; ++o) {
    const float y = fmaf(w1[o][0], X0, fmaf(w1[o][1], X1, fmaf(w1[o][2], X2, bb1[o])));
    a[o] = fmaxf(0.f, fmaf(S[o], y, S[3 + o]));
  }
#pragma unroll
  for (int o = 0; o < 3; ++o) {
    const float y = fmaf(w2[o][0], a[0], fmaf(w2[o][1], a[1], fmaf(w2[o][2], a[2], bb2[o])));
    a2[o] = fmaxf(0.f, fmaf(S[6 + o], y, S[9 + o]));
  }
  float y4 = b4s;
#pragma unroll
  for (int o = 0; o < 3; ++o) {
    const float y = fmaf(w3[o][0], a2[0], fmaf(w3[o][1], a2[1], fmaf(w3[o][2], a2[2], bb3[o])));
    z[o] = fmaf(S[12 + o], y, S[15 + o]);
    y4 = fmaf(w4[o], z[o], y4);
  }
  const float h = fmaxf(0.f, fmaf(S[18], y4, S[19]));
#pragma unroll
  for (int o = 0; o < 3; ++o) p[o] = fmaf(w5[o], h, b5v[o]);
}

// ---------------- pass D: cosine loss ----------------
template <bool BF16>
__global__ __launch_bounds__(256) void passD_kernel(
    const float* __restrict__ x1, const float* __restrict__ x2,
    const ushort_t* __restrict__ xb1, const ushort_t* __restrict__ xb2,
    const float* __restrict__ W1, const float* __restrict__ b1,
    const float* __restrict__ W2, const float* __restrict__ b2,
    const float* __restrict__ W3, const float* __restrict__ b3,
    const float* __restrict__ W4, const float* __restrict__ b4,
    const float* __restrict__ W5, const float* __restrict__ b5,
    const float* __restrict__ derived, double* __restrict__ PL) {
  const int u = blockIdx.y;        // 0..95
  const int n = u % 12;
  const int b = u / 12;
  const size_t off0 = (size_t)((b * NH + n) * 3) * POS + (size_t)blockIdx.x * CSPAN;

  float w1[3][3], bb1[3], w2[3][3], bb2[3], w3[3][3], bb3[3];
  float w4[3], b4s, w5[3], b5v[3];
#pragma unroll
  for (int o = 0; o < 3; ++o) {
#pragma unroll
    for (int c = 0; c < 3; ++c) {
      w1[o][c] = W1[n * 9 + o * 3 + c];
      w2[o][c] = W2[n * 9 + o * 3 + c];
      w3[o][c] = W3[n * 9 + o * 3 + c];
    }
    bb1[o] = b1[n * 3 + o];
    bb2[o] = b2[n * 3 + o];
    bb3[o] = b3[n * 3 + o];
    w4[o]  = W4[n * 3 + o];
    w5[o]  = W5[n * 3 + o];
    b5v[o] = b5[n * 3 + o];
  }
  b4s = b4[n];

  float S0[20], S1[20];
#pragma unroll
  for (int k = 0; k < 20; ++k) {
    S0[k] = derived[(n * 2 + 0) * 20 + k];
    S1[k] = derived[(n * 2 + 1) * 20 + k];
  }

  float acc = 0.f;
  for (int i = 0; i < 4; ++i) {
    const size_t eoff = off0 + i * 2048 + threadIdx.x * 8;
    float fA[3][8], fB[3][8];
    load_ch3<BF16>(x1, xb1, eoff, fA);
    load_ch3<BF16>(x2, xb2, eoff, fB);
#pragma unroll
    for (int j = 0; j < 8; ++j) {
      float z1[3], p1[3], z2[3], p2[3];
      fwd_chain(w1, bb1, w2, bb2, w3, bb3, w4, b4s, w5, b5v, S0,
                fA[0][j], fA[1][j], fA[2][j], z1, p1);
      fwd_chain(w1, bb1, w2, bb2, w3, bb3, w4, b4s, w5, b5v, S1,
                fB[0][j], fB[1][j], fB[2][j], z2, p2);

      const float d12 = p1[0] * z2[0] + p1[1] * z2[1] + p1[2] * z2[2];
      const float pp1 = p1[0] * p1[0] + p1[1] * p1[1] + p1[2] * p1[2];
      const float zz2 = z2[0] * z2[0] + z2[1] * z2[1] + z2[2] * z2[2];
      const float c12 = d12 / (fmaxf(sqrtf(pp1), COS_EPS) * fmaxf(sqrtf(zz2), COS_EPS));

      const float d21 = p2[0] * z1[0] + p2[1] * z1[1] + p2[2] * z1[2];
      const float pp2 = p2[0] * p2[0] + p2[1] * p2[1] + p2[2] * p2[2];
      const float zz1 = z1[0] * z1[0] + z1[1] * z1[1] + z1[2] * z1[2];
      const float c21 = d21 / (fmaxf(sqrtf(pp2), COS_EPS) * fmaxf(sqrtf(zz1), COS_EPS));

      acc += c12 + c21;
    }
  }

  double v[1] = {(double)acc};
  block_reduce_to0<1>(v);
  if (threadIdx.x == 0) PL[(size_t)n * SBLK + b * 16 + blockIdx.x] = v[0];
}

// ---------------- finalize ----------------
__global__ __launch_bounds__(256) void finalize_kernel(
    const double* __restrict__ PL, float* __restrict__ out) {
  double v[1] = {0.0};
  for (int k = threadIdx.x; k < 12 * SBLK; k += 256) v[0] += PL[k];
  block_reduce_to0<1>(v);
  if (threadIdx.x == 0) out[0] = (float)(-0.5 * v[0] / (double)MLL);
}

// ---------------- launch ----------------
extern "C" void kernel_launch(void* const* d_in, const int* in_sizes, int n_in,
                              void* d_out, int out_size, void* d_ws, size_t ws_size,
                              hipStream_t stream) {
  const float* x1  = (const float*)d_in[0];
  const float* x2  = (const float*)d_in[1];
  const float* W1  = (const float*)d_in[2];
  const float* b1  = (const float*)d_in[3];
  const float* g1  = (const float*)d_in[4];
  const float* be1 = (const float*)d_in[5];
  const float* W2  = (const float*)d_in[6];
  const float* b2  = (const float*)d_in[7];
  const float* g2  = (const float*)d_in[8];
  const float* be2 = (const float*)d_in[9];
  const float* W3  = (const float*)d_in[10];
  const float* b3  = (const float*)d_in[11];
  const float* g3  = (const float*)d_in[12];
  const float* be3 = (const float*)d_in[13];
  const float* W4  = (const float*)d_in[14];
  const float* b4  = (const float*)d_in[15];
  const float* g4  = (const float*)d_in[16];
  const float* be4 = (const float*)d_in[17];
  const float* W5  = (const float*)d_in[18];
  const float* b5  = (const float*)d_in[19];

  const bool big = ws_size >= NEED_BYTES;
  ushort_t* xb1 = nullptr;
  ushort_t* xb2 = nullptr;
  double* dbase;
  if (big) {
    xb1 = (ushort_t*)d_ws;
    xb2 = xb1 + NTOT;
    dbase = (double*)(xb2 + NTOT);
  } else {
    dbase = (double*)d_ws;
  }
  double* P0 = dbase;
  double* P2 = P0 + (size_t)24 * SBLK * 9;
  double* P3 = P2 + (size_t)24 * SBLK * 6;
  double* PL = P3 + (size_t)24 * SBLK * 9;
  float* derived = (float*)(PL + 12 * SBLK);

  const dim3 blk(256);
  const dim3 gA(16, 192);
  const dim3 gD(16, 96);

  if (big) {
    passA_kernel<true><<<gA, blk, 0, stream>>>(x1, x2, xb1, xb2, P0);
    bn_statsA_kernel<<<24, blk, 0, stream>>>(P0, W1, b1, g1, be1, derived);
    passB_kernel<true><<<gA, blk, 0, stream>>>(x1, x2, xb1, xb2, W1, b1, W2, b2,
                                               derived, P2);
    bn_statsB_kernel<<<24, blk, 0, stream>>>(P2, g2, be2, derived);
    passC_kernel<true><<<gA, blk, 0, stream>>>(x1, x2, xb1, xb2, W1, b1, W2, b2,
                                               W3, b3, derived, P3);
    bn_statsC_kernel<<<24, blk, 0, stream>>>(P3, g3, be3, W4, b4, g4, be4, derived);
    passD_kernel<true><<<gD, blk, 0, stream>>>(x1, x2, xb1, xb2, W1, b1, W2, b2,
                                               W3, b3, W4, b4, W5, b5, derived, PL);
  } else {
    passA_kernel<false><<<gA, blk, 0, stream>>>(x1, x2, nullptr, nullptr, P0);
    bn_statsA_kernel<<<24, blk, 0, stream>>>(P0, W1, b1, g1, be1, derived);
    passB_kernel<false><<<gA, blk, 0, stream>>>(x1, x2, nullptr, nullptr, W1, b1,
                                                W2, b2, derived, P2);
    bn_statsB_kernel<<<24, blk, 0, stream>>>(P2, g2, be2, derived);
    passC_kernel<false><<<gA, blk, 0, stream>>>(x1, x2, nullptr, nullptr, W1, b1,
                                                W2, b2, W3, b3, derived, P3);
    bn_statsC_kernel<<<24, blk, 0, stream>>>(P3, g3, be3, W4, b4, g4, be4, derived);
    passD_kernel<false><<<gD, blk, 0, stream>>>(x1, x2, nullptr, nullptr, W1, b1,
                                                W2, b2, W3, b3, W4, b4, W5, b5,
                                                derived, PL);
  }
  finalize_kernel<<<1, blk, 0, stream>>>(PL, (float*)d_out);
}